// Round 2
// baseline (3092.954 us; speedup 1.0000x reference)
//
#include <hip/hip_runtime.h>
#include <math.h>

#define B_  8
#define T_  400
#define F_  256
#define D_  64
#define K_  16
#define N_  (T_*F_)        // 102400

// old (fallback) path tiling
#define TILE_OLD 512
#define NBLK_OLD (N_/TILE_OLD)   // 200
// new path tiling
#define TILE 256
#define NBLK (N_/TILE)           // 400

// ---------------- workspace layout (floats) ----------------
// 0      means_s  8192
// 8192   var_s    8192
// 16384  pi_s     128
// 16512  pinv_ck  8192   (old layout [b][c][k][j], fallback path)
// 24704  pw_ck    8192
// 32896  pc0      128
// 33024  cs       128    \
// 33152  sx       8192    > contiguous, zeroed per iteration
// 41344  sx2      8192   /
// 49536  pinv_dk  8192   (new layout [b][d][k])
// 57728  pw_dk    8192
// 65920  xT       52428800  ([b][d][n], only if ws_size permits)

__global__ void initk(const float* __restrict__ means_in,
                      float* __restrict__ means_s, float* __restrict__ var_s,
                      float* __restrict__ pi_s) {
    int i = blockIdx.x * 256 + threadIdx.x;
    if (i < B_*K_*D_) { means_s[i] = means_in[i]; var_s[i] = 1.0f; }
    if (i < B_*K_)    pi_s[i] = 1.0f / K_;
}

// one wave per (b,k): derived params, stored in BOTH layouts
__global__ void prepk(const float* __restrict__ means_s, const float* __restrict__ var_s,
                      const float* __restrict__ pi_s,
                      float* __restrict__ pinv_ck, float* __restrict__ pw_ck,
                      float* __restrict__ pinv_dk, float* __restrict__ pw_dk,
                      float* __restrict__ pc0) {
    int bk = blockIdx.x;          // 0..127
    int b  = bk >> 4;
    int k  = bk & 15;
    int d  = threadIdx.x;         // 0..63
    int idx = bk * D_ + d;
    float var = var_s[idx];
    float m   = means_s[idx];
    float inv = 1.0f / (var + 1e-6f);
    int tck = ((b*16 + (d >> 2))*16 + k)*4 + (d & 3);   // [b][c][k][j]
    pinv_ck[tck] = inv;
    pw_ck[tck]   = m * inv;
    int tdk = (b*64 + d)*16 + k;                        // [b][d][k]
    pinv_dk[tdk] = inv;
    pw_dk[tdk]   = m * inv;
    float r1 = logf(6.283185307179586f * var);   // log(2*pi*var)
    float r2 = m * m * inv;
    #pragma unroll
    for (int off = 32; off > 0; off >>= 1) {
        r1 += __shfl_xor(r1, off);
        r2 += __shfl_xor(r2, off);
    }
    if (d == 0) pc0[bk] = logf(pi_s[bk]) - 0.5f * (r1 + r2);
}

// one-time transpose x[b][n][d] -> xT[b][d][n], 64x64 tiles
__global__ __launch_bounds__(256) void transposek(const float* __restrict__ x,
                                                  float* __restrict__ xT) {
    __shared__ float tile[64][65];
    const int b  = blockIdx.y;
    const int n0 = blockIdx.x * 64;
    const int t  = threadIdx.x;
    const int r  = t >> 4;       // 0..15
    const int c4 = t & 15;       // float4 col
    const float4* src = (const float4*)(x + ((size_t)b*N_ + n0) * D_);
    #pragma unroll
    for (int i = 0; i < 4; ++i) {
        float4 v = src[(r + 16*i) * 16 + c4];
        tile[r + 16*i][4*c4+0] = v.x;
        tile[r + 16*i][4*c4+1] = v.y;
        tile[r + 16*i][4*c4+2] = v.z;
        tile[r + 16*i][4*c4+3] = v.w;
    }
    __syncthreads();
    const int j  = t & 63;       // n within tile
    const int d0 = t >> 6;       // 0..3
    #pragma unroll
    for (int i = 0; i < 16; ++i) {
        int d = d0 * 16 + i;
        xT[((size_t)b*D_ + d) * N_ + n0 + j] = tile[j][d];
    }
}

// ======================= NEW PATH (xT available) =======================
// Phase A: thread owns point n0+t; loops d, coalesced scalar loads from xT,
// params wave-uniform -> s_load broadcasts. Phase B: unchanged coalesced
// pattern on original x, post read from transposed LDS (broadcast, no conflict).
__global__ __launch_bounds__(256, 8) void estepk2(
        const float* __restrict__ xg, const float* __restrict__ xT,
        const float* __restrict__ pinv_dk, const float* __restrict__ pw_dk,
        const float* __restrict__ pc0,
        float* __restrict__ cs, float* __restrict__ sx, float* __restrict__ sx2) {
    __shared__ float postT[16][TILE];     // 16 KB

    const int t  = threadIdx.x;
    const int b  = blockIdx.y;
    const int n0 = blockIdx.x * TILE;

    float c0r[16];
    #pragma unroll
    for (int k = 0; k < 16; ++k) c0r[k] = pc0[b*K_ + k];

    // ---- phase A ----
    const float* xcol = xT + (size_t)b*D_*N_ + n0 + t;
    const float* wv   = pw_dk   + b*D_*K_;
    const float* iv   = pinv_dk + b*D_*K_;

    float t1[16], t2[16];
    #pragma unroll
    for (int k = 0; k < 16; ++k) { t1[k] = 0.f; t2[k] = 0.f; }

    #pragma unroll 8
    for (int d = 0; d < D_; ++d) {
        float xv = xcol[(size_t)d * N_];
        float qv = xv * xv;
        #pragma unroll
        for (int k = 0; k < 16; ++k) {
            t1[k] = fmaf(xv, wv[d*16 + k], t1[k]);    // wave-uniform param
            t2[k] = fmaf(qv, iv[d*16 + k], t2[k]);
        }
    }

    // softmax over K=16 in-thread, post -> postT[k][t] (conflict-free writes)
    {
        float lik[16]; float mx = -1e30f;
        #pragma unroll
        for (int k = 0; k < 16; ++k) { lik[k] = c0r[k] + t1[k] - 0.5f*t2[k]; mx = fmaxf(mx, lik[k]); }
        float s = 0.f;
        #pragma unroll
        for (int k = 0; k < 16; ++k) { lik[k] = __expf(lik[k] - mx); s += lik[k]; }
        float is = 1.0f / s;
        #pragma unroll
        for (int k = 0; k < 16; ++k) postT[k][t] = lik[k] * is;
    }
    __syncthreads();

    // ---- phase B: wave w -> k in [4w,4w+4); lane = (ps<<4)|g ----
    const int lane = t & 63;
    const int kb   = (t >> 6) * 4;
    const int g    = lane & 15;   // d-group
    const int ps   = lane >> 4;   // point phase 0..3

    float sa[4][4], s2a[4][4], ca[4];
    #pragma unroll
    for (int i = 0; i < 4; ++i) {
        ca[i] = 0.f;
        #pragma unroll
        for (int j = 0; j < 4; ++j) { sa[i][j] = 0.f; s2a[i][j] = 0.f; }
    }

    const float4* xq = (const float4*)(xg + ((size_t)b*N_ + n0) * D_);

    #pragma unroll 4
    for (int n = 0; n < TILE; n += 4) {
        const int p = n + ps;
        float4 xv = xq[p*16 + g];
        float pf[4];
        #pragma unroll
        for (int i = 0; i < 4; ++i) pf[i] = postT[kb + i][p];   // LDS broadcast
        float xf[4] = {xv.x, xv.y, xv.z, xv.w};
        float qf[4];
        #pragma unroll
        for (int j = 0; j < 4; ++j) qf[j] = xf[j]*xf[j];
        #pragma unroll
        for (int i = 0; i < 4; ++i) {
            ca[i] += pf[i];
            #pragma unroll
            for (int j = 0; j < 4; ++j) {
                sa[i][j]  = fmaf(pf[i], xf[j], sa[i][j]);
                s2a[i][j] = fmaf(pf[i], qf[j], s2a[i][j]);
            }
        }
    }

    #pragma unroll
    for (int m = 16; m <= 32; m <<= 1) {
        #pragma unroll
        for (int i = 0; i < 4; ++i) {
            ca[i] += __shfl_xor(ca[i], m);
            #pragma unroll
            for (int j = 0; j < 4; ++j) {
                sa[i][j]  += __shfl_xor(sa[i][j],  m);
                s2a[i][j] += __shfl_xor(s2a[i][j], m);
            }
        }
    }

    if (lane < 16) {
        #pragma unroll
        for (int i = 0; i < 4; ++i) {
            #pragma unroll
            for (int j = 0; j < 4; ++j) {
                atomicAdd(&sx [((size_t)(b*K_ + kb + i))*D_ + 4*lane + j], sa[i][j]);
                atomicAdd(&sx2[((size_t)(b*K_ + kb + i))*D_ + 4*lane + j], s2a[i][j]);
            }
        }
        if (lane == 0) {
            #pragma unroll
            for (int i = 0; i < 4; ++i) atomicAdd(&cs[b*K_ + kb + i], ca[i]);
        }
    }
}

__global__ __launch_bounds__(256, 8) void finalk2(
        const float* __restrict__ xT,
        const float* __restrict__ pinv_dk, const float* __restrict__ pw_dk,
        const float* __restrict__ pc0,
        const float* __restrict__ scale, const float* __restrict__ bias,
        float* __restrict__ out) {
    const int t  = threadIdx.x;
    const int b  = blockIdx.y;
    const int n0 = blockIdx.x * TILE;

    float c0r[16];
    #pragma unroll
    for (int k = 0; k < 16; ++k) c0r[k] = pc0[b*K_ + k];

    const float* xcol = xT + (size_t)b*D_*N_ + n0 + t;
    const float* wv   = pw_dk   + b*D_*K_;
    const float* iv   = pinv_dk + b*D_*K_;

    float t1[16], t2[16];
    #pragma unroll
    for (int k = 0; k < 16; ++k) { t1[k] = 0.f; t2[k] = 0.f; }

    #pragma unroll 8
    for (int d = 0; d < D_; ++d) {
        float xv = xcol[(size_t)d * N_];
        float qv = xv * xv;
        #pragma unroll
        for (int k = 0; k < 16; ++k) {
            t1[k] = fmaf(xv, wv[d*16 + k], t1[k]);
            t2[k] = fmaf(qv, iv[d*16 + k], t2[k]);
        }
    }

    const float sc = scale[0], bi = bias[0];
    float4* op = (float4*)(out + ((size_t)b*N_ + n0 + t) * (size_t)K_);
    #pragma unroll
    for (int q = 0; q < 4; ++q) {
        float4 o;
        float z0 = (c0r[4*q+0] + t1[4*q+0] - 0.5f*t2[4*q+0]) * sc + bi;
        float z1 = (c0r[4*q+1] + t1[4*q+1] - 0.5f*t2[4*q+1]) * sc + bi;
        float z2 = (c0r[4*q+2] + t1[4*q+2] - 0.5f*t2[4*q+2]) * sc + bi;
        float z3 = (c0r[4*q+3] + t1[4*q+3] - 0.5f*t2[4*q+3]) * sc + bi;
        o.x = 1.0f / (1.0f + __expf(-z0));
        o.y = 1.0f / (1.0f + __expf(-z1));
        o.z = 1.0f / (1.0f + __expf(-z2));
        o.w = 1.0f / (1.0f + __expf(-z3));
        op[q] = o;
    }
}

// ======================= FALLBACK PATH (small ws) =======================
__global__ __launch_bounds__(256, 5) void estepk(
        const float* __restrict__ xg,
        const float* __restrict__ pinv, const float* __restrict__ pw,
        const float* __restrict__ pc0,
        float* __restrict__ cs, float* __restrict__ sx, float* __restrict__ sx2) {
    __shared__ float post_lds[TILE_OLD * 16];

    const int t  = threadIdx.x;
    const int b  = blockIdx.y;
    const int n0 = blockIdx.x * TILE_OLD;

    const float4* iv4 = (const float4*)(pinv + (size_t)(b*K_*D_));
    const float4* wv4 = (const float4*)(pw   + (size_t)(b*K_*D_));

    float c0r[16];
    #pragma unroll
    for (int k = 0; k < 16; ++k) c0r[k] = pc0[b*K_ + k];

    #pragma unroll 1
    for (int half = 0; half < 2; ++half) {
        const float4* px = (const float4*)(xg + ((size_t)b*N_ + n0 + half*256 + t) * D_);
        float t1[16], t2[16];
        #pragma unroll
        for (int k = 0; k < 16; ++k) { t1[k] = 0.f; t2[k] = 0.f; }
        #pragma unroll 2
        for (int c = 0; c < D_/4; ++c) {
            float4 xv = px[c];
            float4 qv;
            qv.x = xv.x*xv.x; qv.y = xv.y*xv.y; qv.z = xv.z*xv.z; qv.w = xv.w*xv.w;
            const float4* ivc = iv4 + c*16;
            const float4* wvc = wv4 + c*16;
            #pragma unroll
            for (int k = 0; k < 16; ++k) {
                float4 iv = ivc[k];
                float4 wv = wvc[k];
                t2[k] = fmaf(qv.x, iv.x, fmaf(qv.y, iv.y, fmaf(qv.z, iv.z, fmaf(qv.w, iv.w, t2[k]))));
                t1[k] = fmaf(xv.x, wv.x, fmaf(xv.y, wv.y, fmaf(xv.z, wv.z, fmaf(xv.w, wv.w, t1[k]))));
            }
        }
        float lik[16]; float mx = -1e30f;
        #pragma unroll
        for (int k = 0; k < 16; ++k) { lik[k] = c0r[k] + t1[k] - 0.5f*t2[k]; mx = fmaxf(mx, lik[k]); }
        float s = 0.f;
        #pragma unroll
        for (int k = 0; k < 16; ++k) { lik[k] = __expf(lik[k] - mx); s += lik[k]; }
        float is = 1.0f / s;
        #pragma unroll
        for (int k = 0; k < 16; ++k) post_lds[(half*256 + t)*16 + k] = lik[k] * is;
    }
    __syncthreads();

    const int lane = t & 63;
    const int kb   = (t >> 6) * 4;
    const int g    = lane & 15;
    const int ps   = lane >> 4;

    float sa[4][4], s2a[4][4], ca[4];
    #pragma unroll
    for (int i = 0; i < 4; ++i) {
        ca[i] = 0.f;
        #pragma unroll
        for (int j = 0; j < 4; ++j) { sa[i][j] = 0.f; s2a[i][j] = 0.f; }
    }

    const float4* xq = (const float4*)(xg + ((size_t)b*N_ + n0) * D_);

    #pragma unroll 4
    for (int n = 0; n < TILE_OLD; n += 4) {
        const int p = n + ps;
        float4 xv = xq[p*16 + g];
        float4 pv = *(const float4*)&post_lds[p*16 + kb];
        float xf[4] = {xv.x, xv.y, xv.z, xv.w};
        float pf[4] = {pv.x, pv.y, pv.z, pv.w};
        float qf[4];
        #pragma unroll
        for (int j = 0; j < 4; ++j) qf[j] = xf[j]*xf[j];
        #pragma unroll
        for (int i = 0; i < 4; ++i) {
            ca[i] += pf[i];
            #pragma unroll
            for (int j = 0; j < 4; ++j) {
                sa[i][j]  = fmaf(pf[i], xf[j], sa[i][j]);
                s2a[i][j] = fmaf(pf[i], qf[j], s2a[i][j]);
            }
        }
    }

    #pragma unroll
    for (int m = 16; m <= 32; m <<= 1) {
        #pragma unroll
        for (int i = 0; i < 4; ++i) {
            ca[i] += __shfl_xor(ca[i], m);
            #pragma unroll
            for (int j = 0; j < 4; ++j) {
                sa[i][j]  += __shfl_xor(sa[i][j],  m);
                s2a[i][j] += __shfl_xor(s2a[i][j], m);
            }
        }
    }

    if (lane < 16) {
        #pragma unroll
        for (int i = 0; i < 4; ++i) {
            #pragma unroll
            for (int j = 0; j < 4; ++j) {
                atomicAdd(&sx [((size_t)(b*K_ + kb + i))*D_ + 4*lane + j], sa[i][j]);
                atomicAdd(&sx2[((size_t)(b*K_ + kb + i))*D_ + 4*lane + j], s2a[i][j]);
            }
        }
        if (lane == 0) {
            #pragma unroll
            for (int i = 0; i < 4; ++i) atomicAdd(&cs[b*K_ + kb + i], ca[i]);
        }
    }
}

__global__ __launch_bounds__(256, 5) void finalk(
        const float* __restrict__ xg,
        const float* __restrict__ pinv, const float* __restrict__ pw,
        const float* __restrict__ pc0,
        const float* __restrict__ scale, const float* __restrict__ bias,
        float* __restrict__ out) {
    const int t  = threadIdx.x;
    const int b  = blockIdx.y;
    const int n0 = blockIdx.x * TILE_OLD;

    const float4* iv4 = (const float4*)(pinv + (size_t)(b*K_*D_));
    const float4* wv4 = (const float4*)(pw   + (size_t)(b*K_*D_));

    float c0r[16];
    #pragma unroll
    for (int k = 0; k < 16; ++k) c0r[k] = pc0[b*K_ + k];

    const float sc = scale[0], bi = bias[0];

    #pragma unroll 1
    for (int half = 0; half < 2; ++half) {
        const float4* px = (const float4*)(xg + ((size_t)b*N_ + n0 + half*256 + t) * D_);
        float t1[16], t2[16];
        #pragma unroll
        for (int k = 0; k < 16; ++k) { t1[k] = 0.f; t2[k] = 0.f; }
        #pragma unroll 2
        for (int c = 0; c < D_/4; ++c) {
            float4 xv = px[c];
            float4 qv;
            qv.x = xv.x*xv.x; qv.y = xv.y*xv.y; qv.z = xv.z*xv.z; qv.w = xv.w*xv.w;
            const float4* ivc = iv4 + c*16;
            const float4* wvc = wv4 + c*16;
            #pragma unroll
            for (int k = 0; k < 16; ++k) {
                float4 iv = ivc[k];
                float4 wv = wvc[k];
                t2[k] = fmaf(qv.x, iv.x, fmaf(qv.y, iv.y, fmaf(qv.z, iv.z, fmaf(qv.w, iv.w, t2[k]))));
                t1[k] = fmaf(xv.x, wv.x, fmaf(xv.y, wv.y, fmaf(xv.z, wv.z, fmaf(xv.w, wv.w, t1[k]))));
            }
        }
        float4* op = (float4*)(out + ((size_t)b*N_ + n0 + half*256 + t) * (size_t)K_);
        #pragma unroll
        for (int q = 0; q < 4; ++q) {
            float4 o;
            float z0 = (c0r[4*q+0] + t1[4*q+0] - 0.5f*t2[4*q+0]) * sc + bi;
            float z1 = (c0r[4*q+1] + t1[4*q+1] - 0.5f*t2[4*q+1]) * sc + bi;
            float z2 = (c0r[4*q+2] + t1[4*q+2] - 0.5f*t2[4*q+2]) * sc + bi;
            float z3 = (c0r[4*q+3] + t1[4*q+3] - 0.5f*t2[4*q+3]) * sc + bi;
            o.x = 1.0f / (1.0f + __expf(-z0));
            o.y = 1.0f / (1.0f + __expf(-z1));
            o.z = 1.0f / (1.0f + __expf(-z2));
            o.w = 1.0f / (1.0f + __expf(-z3));
            op[q] = o;
        }
    }
}

__global__ void mstepk(float* __restrict__ means_s, float* __restrict__ var_s,
                       float* __restrict__ pi_s,
                       const float* __restrict__ cs, const float* __restrict__ sx,
                       const float* __restrict__ sx2) {
    int idx = blockIdx.x * 256 + threadIdx.x;   // < 8192
    int b = idx >> 10;
    int k = (idx >> 6) & 15;
    int d = idx & 63;
    float csv = cs[b*K_ + k];
    float sum = 0.f;
    #pragma unroll
    for (int j = 0; j < 16; ++j) sum += cs[b*K_ + j];
    float sxv = sx[idx], sx2v = sx2[idx];
    float mean = sxv / (csv + 1e-7f);
    float var  = fmaf(mean*mean, csv, fmaf(-2.0f*mean, sxv, sx2v)) + 1e-6f;
    means_s[idx] = mean;
    var_s[idx]   = var;
    if (d == 0) pi_s[b*K_ + k] = csv / sum;
}

extern "C" void kernel_launch(void* const* d_in, const int* in_sizes, int n_in,
                              void* d_out, int out_size, void* d_ws, size_t ws_size,
                              hipStream_t stream) {
    const float* xg       = (const float*)d_in[0];
    const float* means_in = (const float*)d_in[1];
    const float* scale    = (const float*)d_in[2];
    const float* bias     = (const float*)d_in[3];
    float* out = (float*)d_out;

    float* ws       = (float*)d_ws;
    float* means_s  = ws + 0;
    float* var_s    = ws + 8192;
    float* pi_s     = ws + 16384;
    float* pinv_ck  = ws + 16512;
    float* pw_ck    = ws + 24704;
    float* pc0      = ws + 32896;
    float* cs       = ws + 33024;
    float* sx       = ws + 33152;
    float* sx2      = ws + 41344;
    float* pinv_dk  = ws + 49536;
    float* pw_dk    = ws + 57728;
    float* xT       = ws + 65920;

    const size_t need_floats = (size_t)65920 + (size_t)B_ * D_ * N_;  // ~210 MB
    const bool big = ws_size >= need_floats * sizeof(float);

    initk<<<dim3(32), dim3(256), 0, stream>>>(means_in, means_s, var_s, pi_s);
    if (big) transposek<<<dim3(N_/64, B_), dim3(256), 0, stream>>>(xg, xT);

    for (int it = 0; it < 5; ++it) {
        prepk<<<dim3(B_*K_), dim3(64), 0, stream>>>(means_s, var_s, pi_s,
                                                    pinv_ck, pw_ck, pinv_dk, pw_dk, pc0);
        hipMemsetAsync(cs, 0, (size_t)(128 + 8192 + 8192) * sizeof(float), stream);
        if (big)
            estepk2<<<dim3(NBLK, B_), dim3(256), 0, stream>>>(xg, xT, pinv_dk, pw_dk, pc0, cs, sx, sx2);
        else
            estepk<<<dim3(NBLK_OLD, B_), dim3(256), 0, stream>>>(xg, pinv_ck, pw_ck, pc0, cs, sx, sx2);
        mstepk<<<dim3(32), dim3(256), 0, stream>>>(means_s, var_s, pi_s, cs, sx, sx2);
    }
    prepk<<<dim3(B_*K_), dim3(64), 0, stream>>>(means_s, var_s, pi_s,
                                                pinv_ck, pw_ck, pinv_dk, pw_dk, pc0);
    if (big)
        finalk2<<<dim3(NBLK, B_), dim3(256), 0, stream>>>(xT, pinv_dk, pw_dk, pc0, scale, bias, out);
    else
        finalk<<<dim3(NBLK_OLD, B_), dim3(256), 0, stream>>>(xg, pinv_ck, pw_ck, pc0, scale, bias, out);
}

// Round 3
// 1116.020 us; speedup vs baseline: 2.7714x; 2.7714x over previous
//
#include <hip/hip_runtime.h>
#include <math.h>

#define B_  8
#define T_  400
#define F_  256
#define D_  64
#define K_  16
#define N_  (T_*F_)        // 102400
#define TILE 256
#define NBLK (N_/TILE)     // 400
#define PSLOT 2064         // floats per partial slot: 1024 sx + 1024 sx2 + 16 cs
#define SG 8               // slot groups in reducek
#define SPG (NBLK/SG)      // 50

// ---------------- workspace layout (floats) ----------------
// 0      means_s 8192
// 8192   var_s   8192
// 16384  pi_s    128
// 16512  pinv    8192   [b][c][k][j], c=d/4, j=d%4
// 24704  pw      8192
// 32896  pc0     128
// 33024  cs      128    \
// 33152  sx      8192    > contiguous, zeroed per iteration (sx2 = sx+8192)
// 41344  sx2     8192   /
// 49536  part    B_*NBLK*PSLOT = 6,604,800  (~26.4 MB)

__global__ void initk(const float* __restrict__ means_in,
                      float* __restrict__ means_s, float* __restrict__ var_s,
                      float* __restrict__ pi_s) {
    int i = blockIdx.x * 256 + threadIdx.x;
    if (i < B_*K_*D_) { means_s[i] = means_in[i]; var_s[i] = 1.0f; }
    if (i < B_*K_)    pi_s[i] = 1.0f / K_;
}

// one wave per (b,k): derived params in [b][c][k][j] layout
__global__ void prepk(const float* __restrict__ means_s, const float* __restrict__ var_s,
                      const float* __restrict__ pi_s,
                      float* __restrict__ pinv, float* __restrict__ pw,
                      float* __restrict__ pc0) {
    int bk = blockIdx.x;          // 0..127
    int b  = bk >> 4;
    int k  = bk & 15;
    int d  = threadIdx.x;         // 0..63
    int idx = bk * D_ + d;
    float var = var_s[idx];
    float m   = means_s[idx];
    float inv = 1.0f / (var + 1e-6f);
    int tck = ((b*16 + (d >> 2))*16 + k)*4 + (d & 3);   // [b][c][k][j]
    pinv[tck] = inv;
    pw[tck]   = m * inv;
    float r1 = logf(6.283185307179586f * var);   // log(2*pi*var)
    float r2 = m * m * inv;
    #pragma unroll
    for (int off = 32; off > 0; off >>= 1) {
        r1 += __shfl_xor(r1, off);
        r2 += __shfl_xor(r2, off);
    }
    if (d == 0) pc0[bk] = logf(pi_s[bk]) - 0.5f * (r1 + r2);
}

// fused E-step: lik -> softmax -> post in LDS -> coalesced accumulate ->
// per-block partial stores (no atomics). One point per thread in phase A.
__global__ __launch_bounds__(256, 6) void estepk(
        const float* __restrict__ xg,
        const float* __restrict__ pinv, const float* __restrict__ pw,
        const float* __restrict__ pc0,
        float* __restrict__ cs, float* __restrict__ sx, float* __restrict__ sx2,
        float* __restrict__ part) {
    __shared__ float post_lds[TILE * 16];     // 16 KB

    const int t  = threadIdx.x;
    const int b  = blockIdx.y;
    const int n0 = blockIdx.x * TILE;

    const float4* iv4 = (const float4*)(pinv + (size_t)(b*K_*D_));  // uniform reads
    const float4* wv4 = (const float4*)(pw   + (size_t)(b*K_*D_));

    float c0r[16];
    #pragma unroll
    for (int k = 0; k < 16; ++k) c0r[k] = pc0[b*K_ + k];

    // ---- phase A: one point per thread ----
    const float4* px = (const float4*)(xg + ((size_t)b*N_ + n0 + t) * D_);

    float t1[16], t2[16];
    #pragma unroll
    for (int k = 0; k < 16; ++k) { t1[k] = 0.f; t2[k] = 0.f; }

    #pragma unroll 4
    for (int c = 0; c < D_/4; ++c) {
        float4 xv = px[c];
        float4 qv;
        qv.x = xv.x*xv.x; qv.y = xv.y*xv.y; qv.z = xv.z*xv.z; qv.w = xv.w*xv.w;
        const float4* ivc = iv4 + c*16;
        const float4* wvc = wv4 + c*16;
        #pragma unroll
        for (int k = 0; k < 16; ++k) {
            float4 iv = ivc[k];           // wave-uniform
            float4 wv = wvc[k];
            t2[k] = fmaf(qv.x, iv.x, fmaf(qv.y, iv.y, fmaf(qv.z, iv.z, fmaf(qv.w, iv.w, t2[k]))));
            t1[k] = fmaf(xv.x, wv.x, fmaf(xv.y, wv.y, fmaf(xv.z, wv.z, fmaf(xv.w, wv.w, t1[k]))));
        }
    }

    // softmax over K=16 in-thread, post -> LDS
    {
        float lik[16]; float mx = -1e30f;
        #pragma unroll
        for (int k = 0; k < 16; ++k) { lik[k] = c0r[k] + t1[k] - 0.5f*t2[k]; mx = fmaxf(mx, lik[k]); }
        float s = 0.f;
        #pragma unroll
        for (int k = 0; k < 16; ++k) { lik[k] = __expf(lik[k] - mx); s += lik[k]; }
        float is = 1.0f / s;
        #pragma unroll
        for (int k = 0; k < 16; ++k) post_lds[t*16 + k] = lik[k] * is;
    }
    __syncthreads();

    // ---- phase B: wave w -> k in [4w,4w+4); lane = (ps<<4)|g ----
    const int lane = t & 63;
    const int kb   = (t >> 6) * 4;
    const int g    = lane & 15;   // d-group: d = 4g..4g+3
    const int ps   = lane >> 4;   // point phase 0..3

    float sa[4][4], s2a[4][4], ca[4];
    #pragma unroll
    for (int i = 0; i < 4; ++i) {
        ca[i] = 0.f;
        #pragma unroll
        for (int j = 0; j < 4; ++j) { sa[i][j] = 0.f; s2a[i][j] = 0.f; }
    }

    const float4* xq = (const float4*)(xg + ((size_t)b*N_ + n0) * D_);

    #pragma unroll 4
    for (int n = 0; n < TILE; n += 4) {
        const int p = n + ps;
        float4 xv = xq[p*16 + g];
        float4 pv = *(const float4*)&post_lds[p*16 + kb];
        float xf[4] = {xv.x, xv.y, xv.z, xv.w};
        float pf[4] = {pv.x, pv.y, pv.z, pv.w};
        float qf[4];
        #pragma unroll
        for (int j = 0; j < 4; ++j) qf[j] = xf[j]*xf[j];
        #pragma unroll
        for (int i = 0; i < 4; ++i) {
            ca[i] += pf[i];
            #pragma unroll
            for (int j = 0; j < 4; ++j) {
                sa[i][j]  = fmaf(pf[i], xf[j], sa[i][j]);
                s2a[i][j] = fmaf(pf[i], qf[j], s2a[i][j]);
            }
        }
    }

    // reduce across the 4 point-phases (xor 16, then xor 32)
    #pragma unroll
    for (int m = 16; m <= 32; m <<= 1) {
        #pragma unroll
        for (int i = 0; i < 4; ++i) {
            ca[i] += __shfl_xor(ca[i], m);
            #pragma unroll
            for (int j = 0; j < 4; ++j) {
                sa[i][j]  += __shfl_xor(sa[i][j],  m);
                s2a[i][j] += __shfl_xor(s2a[i][j], m);
            }
        }
    }

    if (part) {
        // per-block partial slot, coalesced float4 stores, no atomics
        float* pp = part + ((size_t)(b*NBLK + blockIdx.x)) * PSLOT;
        if (lane < 16) {
            #pragma unroll
            for (int i = 0; i < 4; ++i) {
                float4 v1 = make_float4(sa[i][0],  sa[i][1],  sa[i][2],  sa[i][3]);
                float4 v2 = make_float4(s2a[i][0], s2a[i][1], s2a[i][2], s2a[i][3]);
                *(float4*)&pp[(kb + i)*64 + 4*lane]        = v1;
                *(float4*)&pp[1024 + (kb + i)*64 + 4*lane] = v2;
            }
            if (lane == 0) {
                #pragma unroll
                for (int i = 0; i < 4; ++i) pp[2048 + kb + i] = ca[i];
            }
        }
    } else {
        if (lane < 16) {
            #pragma unroll
            for (int i = 0; i < 4; ++i) {
                #pragma unroll
                for (int j = 0; j < 4; ++j) {
                    atomicAdd(&sx [((size_t)(b*K_ + kb + i))*D_ + 4*lane + j], sa[i][j]);
                    atomicAdd(&sx2[((size_t)(b*K_ + kb + i))*D_ + 4*lane + j], s2a[i][j]);
                }
            }
            if (lane == 0) {
                #pragma unroll
                for (int i = 0; i < 4; ++i) atomicAdd(&cs[b*K_ + kb + i], ca[i]);
            }
        }
    }
}

// fold NBLK partial slots into cs/sx/sx2. grid (65, SG); each block sums SPG
// slots; 8 atomic folds per output element total.
__global__ __launch_bounds__(256) void reducek(const float* __restrict__ part,
                                               float* __restrict__ cs,
                                               float* __restrict__ sx) {
    const int idx = blockIdx.x * 256 + threadIdx.x;
    const int s0  = blockIdx.y * SPG;
    if (idx < B_*2048) {
        const int b = idx >> 11, off = idx & 2047;
        const float* pp = part + ((size_t)(b*NBLK + s0)) * PSLOT + off;
        float sum = 0.f;
        #pragma unroll 10
        for (int s = 0; s < SPG; ++s) sum += pp[(size_t)s * PSLOT];
        float* dst = (off < 1024) ? (sx + b*1024 + off)
                                  : (sx + 8192 + b*1024 + (off - 1024));   // sx2
        atomicAdd(dst, sum);
    } else if (idx < B_*2048 + B_*K_) {
        const int c = idx - B_*2048;
        const int b = c >> 4, k = c & 15;
        const float* pp = part + ((size_t)(b*NBLK + s0)) * PSLOT + 2048 + k;
        float sum = 0.f;
        #pragma unroll 10
        for (int s = 0; s < SPG; ++s) sum += pp[(size_t)s * PSLOT];
        atomicAdd(&cs[b*16 + k], sum);
    }
}

__global__ void mstepk(float* __restrict__ means_s, float* __restrict__ var_s,
                       float* __restrict__ pi_s,
                       const float* __restrict__ cs, const float* __restrict__ sx,
                       const float* __restrict__ sx2) {
    int idx = blockIdx.x * 256 + threadIdx.x;   // < 8192
    int b = idx >> 10;
    int k = (idx >> 6) & 15;
    int d = idx & 63;
    float csv = cs[b*K_ + k];
    float sum = 0.f;
    #pragma unroll
    for (int j = 0; j < 16; ++j) sum += cs[b*K_ + j];
    float sxv = sx[idx], sx2v = sx2[idx];
    float mean = sxv / (csv + 1e-7f);
    float var  = fmaf(mean*mean, csv, fmaf(-2.0f*mean, sxv, sx2v)) + 1e-6f;
    means_s[idx] = mean;
    var_s[idx]   = var;
    if (d == 0) pi_s[b*K_ + k] = csv / sum;
}

// final lik -> sigmoid(scale*lik + bias) -> out[b][n][k]; one point per thread
__global__ __launch_bounds__(256, 6) void finalk(
        const float* __restrict__ xg,
        const float* __restrict__ pinv, const float* __restrict__ pw,
        const float* __restrict__ pc0,
        const float* __restrict__ scale, const float* __restrict__ bias,
        float* __restrict__ out) {
    const int t  = threadIdx.x;
    const int b  = blockIdx.y;
    const int n0 = blockIdx.x * TILE;

    const float4* iv4 = (const float4*)(pinv + (size_t)(b*K_*D_));
    const float4* wv4 = (const float4*)(pw   + (size_t)(b*K_*D_));

    float c0r[16];
    #pragma unroll
    for (int k = 0; k < 16; ++k) c0r[k] = pc0[b*K_ + k];

    const float4* px = (const float4*)(xg + ((size_t)b*N_ + n0 + t) * D_);

    float t1[16], t2[16];
    #pragma unroll
    for (int k = 0; k < 16; ++k) { t1[k] = 0.f; t2[k] = 0.f; }

    #pragma unroll 4
    for (int c = 0; c < D_/4; ++c) {
        float4 xv = px[c];
        float4 qv;
        qv.x = xv.x*xv.x; qv.y = xv.y*xv.y; qv.z = xv.z*xv.z; qv.w = xv.w*xv.w;
        const float4* ivc = iv4 + c*16;
        const float4* wvc = wv4 + c*16;
        #pragma unroll
        for (int k = 0; k < 16; ++k) {
            float4 iv = ivc[k];
            float4 wv = wvc[k];
            t2[k] = fmaf(qv.x, iv.x, fmaf(qv.y, iv.y, fmaf(qv.z, iv.z, fmaf(qv.w, iv.w, t2[k]))));
            t1[k] = fmaf(xv.x, wv.x, fmaf(xv.y, wv.y, fmaf(xv.z, wv.z, fmaf(xv.w, wv.w, t1[k]))));
        }
    }

    const float sc = scale[0], bi = bias[0];
    float4* op = (float4*)(out + ((size_t)b*N_ + n0 + t) * (size_t)K_);
    #pragma unroll
    for (int q = 0; q < 4; ++q) {
        float4 o;
        float z0 = (c0r[4*q+0] + t1[4*q+0] - 0.5f*t2[4*q+0]) * sc + bi;
        float z1 = (c0r[4*q+1] + t1[4*q+1] - 0.5f*t2[4*q+1]) * sc + bi;
        float z2 = (c0r[4*q+2] + t1[4*q+2] - 0.5f*t2[4*q+2]) * sc + bi;
        float z3 = (c0r[4*q+3] + t1[4*q+3] - 0.5f*t2[4*q+3]) * sc + bi;
        o.x = 1.0f / (1.0f + __expf(-z0));
        o.y = 1.0f / (1.0f + __expf(-z1));
        o.z = 1.0f / (1.0f + __expf(-z2));
        o.w = 1.0f / (1.0f + __expf(-z3));
        op[q] = o;
    }
}

extern "C" void kernel_launch(void* const* d_in, const int* in_sizes, int n_in,
                              void* d_out, int out_size, void* d_ws, size_t ws_size,
                              hipStream_t stream) {
    const float* xg       = (const float*)d_in[0];
    const float* means_in = (const float*)d_in[1];
    const float* scale    = (const float*)d_in[2];
    const float* bias     = (const float*)d_in[3];
    float* out = (float*)d_out;

    float* ws      = (float*)d_ws;
    float* means_s = ws + 0;
    float* var_s   = ws + 8192;
    float* pi_s    = ws + 16384;
    float* pinv    = ws + 16512;
    float* pw      = ws + 24704;
    float* pc0     = ws + 32896;
    float* cs      = ws + 33024;
    float* sx      = ws + 33152;
    // sx2 = sx + 8192 (contiguous; reducek relies on this)
    float* sx2     = ws + 41344;
    float* part    = ws + 49536;

    const size_t need_floats = (size_t)49536 + (size_t)B_ * NBLK * PSLOT;  // ~26.6 MB
    if (ws_size < need_floats * sizeof(float)) part = nullptr;

    initk<<<dim3(32), dim3(256), 0, stream>>>(means_in, means_s, var_s, pi_s);

    for (int it = 0; it < 5; ++it) {
        prepk<<<dim3(B_*K_), dim3(64), 0, stream>>>(means_s, var_s, pi_s, pinv, pw, pc0);
        hipMemsetAsync(cs, 0, (size_t)(128 + 8192 + 8192) * sizeof(float), stream);
        estepk<<<dim3(NBLK, B_), dim3(256), 0, stream>>>(xg, pinv, pw, pc0, cs, sx, sx2, part);
        if (part)
            reducek<<<dim3(65, SG), dim3(256), 0, stream>>>(part, cs, sx);
        mstepk<<<dim3(32), dim3(256), 0, stream>>>(means_s, var_s, pi_s, cs, sx, sx2);
    }
    prepk<<<dim3(B_*K_), dim3(64), 0, stream>>>(means_s, var_s, pi_s, pinv, pw, pc0);
    finalk<<<dim3(NBLK, B_), dim3(256), 0, stream>>>(xg, pinv, pw, pc0, scale, bias, out);
}